// Round 4
// baseline (922.032 us; speedup 1.0000x reference)
//
#include <hip/hip_runtime.h>
#include <cmath>

#define LSEQ   512
#define BATCH  128
#define EDIM   256
#define HDIM   128
#define GDIM   512      // 4*H2
#define NVOC   32001    // V+1 rows in emb table
#define PADROW 32000    // pad_id

typedef __attribute__((ext_vector_type(4))) float f32x4;

// ---------------------------------------------------------------------------
// Kernel 1: G[dir][v][n] = sum_e emb[v][e]*W_ih[n][e] + b[n], pure f32 VALU.
// Tile 64x64, K-panels of 32 in LDS, 256 threads, 4x4 register blocking.
// ---------------------------------------------------------------------------
__global__ __launch_bounds__(256) void g_gemm_f32(
    const float* __restrict__ emb,
    const float* __restrict__ Wf, const float* __restrict__ Wb,
    const float* __restrict__ bf, const float* __restrict__ bb,
    float* __restrict__ G)
{
    const int mb  = blockIdx.x;   // 0..500   (vocab tiles)
    const int nb  = blockIdx.y;   // 0..7     (gate-col tiles)
    const int dir = blockIdx.z;   // 0..1
    const float* W    = dir ? Wb : Wf;
    const float* bias = dir ? bb : bf;
    float* Gd = G + (size_t)dir * NVOC * GDIM;

    __shared__ float As[32][68];   // [k][m], pad 68 -> 272B row stride (16B aligned)
    __shared__ float Bs[32][68];   // [k][n]

    const int tid = threadIdx.x;
    const int tx  = tid & 15;      // n sub-tile
    const int ty  = tid >> 4;      // m sub-tile
    const int m0  = mb * 64;
    const int n0  = nb * 64;

    float acc[4][4] = {};

    for (int k0 = 0; k0 < EDIM; k0 += 32) {
        __syncthreads();
        #pragma unroll
        for (int it = 0; it < 8; ++it) {
            int e = tid + 256 * it;     // 0..2047
            int k = e & 31;
            int m = e >> 5;             // 0..63
            int v = m0 + m; if (v > PADROW) v = PADROW;
            As[k][m] = emb[(size_t)v * EDIM + k0 + k];
            Bs[k][m] = W[(size_t)(n0 + m) * EDIM + k0 + k];
        }
        __syncthreads();
        #pragma unroll
        for (int k = 0; k < 32; ++k) {
            f32x4 a  = *(const f32x4*)&As[k][4 * ty];
            f32x4 bv = *(const f32x4*)&Bs[k][4 * tx];
            #pragma unroll
            for (int i = 0; i < 4; ++i)
                #pragma unroll
                for (int j = 0; j < 4; ++j)
                    acc[i][j] = fmaf(a[i], bv[j], acc[i][j]);
        }
    }

    f32x4 b4 = *(const f32x4*)&bias[n0 + 4 * tx];
    #pragma unroll
    for (int i = 0; i < 4; ++i) {
        int v = m0 + 4 * ty + i;
        if (v < NVOC) {
            f32x4 o = { acc[i][0] + b4.x, acc[i][1] + b4.y,
                        acc[i][2] + b4.z, acc[i][3] + b4.w };
            *(f32x4*)&Gd[(size_t)v * GDIM + n0 + 4 * tx] = o;
        }
    }
}

// ---------------------------------------------------------------------------
// Kernel 2: LSTM scan, pure f32 VALU. One (dir,b) per block, 512 threads.
// Thread t owns gate n = t: W_hh row in 128 VGPRs; h broadcast from LDS.
// Threads 0..127 own the c/h update for h-column tid.
// ---------------------------------------------------------------------------
__global__ __launch_bounds__(512) void lstm_scan_f32(
    const int*   __restrict__ tokens,
    const float* __restrict__ Whh_f, const float* __restrict__ Whh_b,
    const float* __restrict__ G,
    float* __restrict__ out)
{
    const int dir = blockIdx.x >> 7;
    const int b   = blockIdx.x & 127;
    const float* Whh = dir ? Whh_b : Whh_f;
    const float* Gd  = G + (size_t)dir * NVOC * GDIM;

    __shared__ int   tok[LSEQ];
    __shared__ float hbuf[2][HDIM];
    __shared__ float gl[GDIM];

    const int tid = threadIdx.x;          // gate index n = tid
    tok[tid] = tokens[(size_t)tid * BATCH + b];
    if (tid < HDIM) { hbuf[0][tid] = 0.f; hbuf[1][tid] = 0.f; }

    // W_hh row tid -> registers (statically indexed, fully unrolled)
    float wreg[HDIM];
    #pragma unroll
    for (int k4 = 0; k4 < 32; ++k4) {
        f32x4 wv = *(const f32x4*)(Whh + (size_t)tid * HDIM + 4 * k4);
        wreg[4 * k4 + 0] = wv.x; wreg[4 * k4 + 1] = wv.y;
        wreg[4 * k4 + 2] = wv.z; wreg[4 * k4 + 3] = wv.w;
    }
    __syncthreads();

    auto rowof = [&](int t) -> int {
        int l  = dir ? (LSEQ - 1 - t) : t;
        int tk = tok[l];
        return (tk < 0) ? PADROW : tk;
    };

    float c      = 0.f;
    float xg_cur = Gd[(size_t)rowof(0) * GDIM + tid];

    for (int t = 0; t < LSEQ; ++t) {
        int l = dir ? (LSEQ - 1 - t) : t;
        // prefetch next step's xg (hidden under this step's compute)
        float xg_nxt = (t + 1 < LSEQ) ? Gd[(size_t)rowof(t + 1) * GDIM + tid] : 0.f;

        const float* hb = hbuf[t & 1];
        float a0 = xg_cur, a1 = 0.f, a2 = 0.f, a3 = 0.f;
        #pragma unroll
        for (int k4 = 0; k4 < 32; ++k4) {
            f32x4 hv = *(const f32x4*)&hb[4 * k4];   // broadcast read (same addr all lanes)
            a0 = fmaf(hv.x, wreg[4 * k4 + 0], a0);
            a1 = fmaf(hv.y, wreg[4 * k4 + 1], a1);
            a2 = fmaf(hv.z, wreg[4 * k4 + 2], a2);
            a3 = fmaf(hv.w, wreg[4 * k4 + 3], a3);
        }
        gl[tid] = (a0 + a1) + (a2 + a3);
        __syncthreads();

        if (tid < HDIM) {
            float iv = 1.f / (1.f + expf(-gl[tid]));
            float fv = 1.f / (1.f + expf(-gl[tid + 128]));
            float gv = tanhf(gl[tid + 256]);
            float ov = 1.f / (1.f + expf(-gl[tid + 384]));
            c = fv * c + iv * gv;
            float h = ov * tanhf(c);
            if (tok[l] < 0) { c = 0.f; h = 0.f; }
            out[(size_t)l * (BATCH * 256) + (size_t)b * 256 + dir * HDIM + tid] = h;
            hbuf[(t + 1) & 1][tid] = h;
        }
        __syncthreads();
        xg_cur = xg_nxt;
    }
}

// ---------------------------------------------------------------------------
extern "C" void kernel_launch(void* const* d_in, const int* in_sizes, int n_in,
                              void* d_out, int out_size, void* d_ws, size_t ws_size,
                              hipStream_t stream) {
    const int*   tokens = (const int*)  d_in[0];
    // d_in[1] = mask (unused; token==-1 <=> mask==0)
    const float* emb    = (const float*)d_in[2];
    const float* W_ih_f = (const float*)d_in[3];
    const float* W_hh_f = (const float*)d_in[4];
    const float* b_f    = (const float*)d_in[5];
    const float* W_ih_b = (const float*)d_in[6];
    const float* W_hh_b = (const float*)d_in[7];
    const float* b_b    = (const float*)d_in[8];

    float* G = (float*)d_ws;   // [2][NVOC][512] f32 = 131 MB

    g_gemm_f32<<<dim3(501, 8, 2), 256, 0, stream>>>(emb, W_ih_f, W_ih_b, b_f, b_b, G);
    lstm_scan_f32<<<256, 512, 0, stream>>>(tokens, W_hh_f, W_hh_b, G,
                                           (float*)d_out);
}